// Round 1
// baseline (15527.881 us; speedup 1.0000x reference)
//
#include <hip/hip_runtime.h>
#include <stdint.h>

// LSTM: B=256, T=512, D=128, H=512, C=10
// Persistent kernel: 16 groups x 32 blocks (512 blocks, 128 thr = 2 waves).
// Group owns 16 batches; block owns 16 hidden units (64 gate rows: i,f,g,o x16).
// W_ih/W_hh slices live in VGPRs as fp16 MFMA A-fragments (~160 VGPR/wave).
// h exchanged via global fp16 double-buffer + per-group counter barrier/step.

#define T_STEPS 512
#define BATCH   256
#define DIM     128
#define HID     512
#define NGRP    16
#define GBLK    32
#define BT      16   // batches per group

typedef _Float16 half8 __attribute__((ext_vector_type(8)));
typedef _Float16 half4 __attribute__((ext_vector_type(4)));
typedef float    f32x4 __attribute__((ext_vector_type(4)));

// ws layout: [0, 512KB) h double-buffer fp16 [2][256][512]; then counters (128B stride x16)
#define HBUF_HALFS   (2 * BATCH * HID)
#define CNT_OFF      (HBUF_HALFS * 2)          // 524288 bytes
#define WS_NEEDED    (CNT_OFF + NGRP * 128)

__device__ __forceinline__ half8 load8_cvt(const float* p) {
  const f32x4* q = (const f32x4*)p;
  f32x4 a = q[0], b = q[1];
  half8 r;
  r[0]=(_Float16)a[0]; r[1]=(_Float16)a[1]; r[2]=(_Float16)a[2]; r[3]=(_Float16)a[3];
  r[4]=(_Float16)b[0]; r[5]=(_Float16)b[1]; r[6]=(_Float16)b[2]; r[7]=(_Float16)b[3];
  return r;
}

__global__ __launch_bounds__(128, 1) void lstm_persistent(
    const float* __restrict__ X,   const float* __restrict__ Wih,
    const float* __restrict__ Whh, const float* __restrict__ bih,
    const float* __restrict__ bhh, const float* __restrict__ Wlin,
    float* __restrict__ out, _Float16* __restrict__ hbuf,
    unsigned int* __restrict__ cnt)
{
  __shared__ float scratch[16 * 64];  // K-split partial exchange (4 KB)

  const int tid   = threadIdx.x;
  const int khalf = tid >> 6;        // wave 0: k in [0,320); wave 1: k in [320,640)
  const int lane  = tid & 63;
  const int col   = lane & 15;       // MFMA A-row m / B,C col n
  const int q     = lane >> 4;       // 0..3
  const int bid   = blockIdx.x;
  const int g     = bid & 15;        // group; blocks of a group share bid%8 -> same XCD (heuristic)
  const int J     = (bid >> 4) * 16; // hidden-unit base owned by this block
  const int bg0   = g * BT;
  const int b_my  = bg0 + col;       // this lane's batch (B-frag n and C col)

  // ---- load W fragments into registers (once) ----
  half8 whh[8][4];                   // [local k-chunk][gate]
  half8 wih[2][4];
  #pragma unroll
  for (int lc = 0; lc < 8; ++lc) {
    const int kc = khalf * 8 + lc;
    #pragma unroll
    for (int mt = 0; mt < 4; ++mt) {
      const int row = mt * HID + J + col;
      whh[lc][mt] = load8_cvt(Whh + (size_t)row * HID + kc * 32 + q * 8);
    }
  }
  #pragma unroll
  for (int lx = 0; lx < 2; ++lx) {
    const int xc = khalf * 2 + lx;
    #pragma unroll
    for (int mt = 0; mt < 4; ++mt) {
      const int row = mt * HID + J + col;
      wih[lx][mt] = load8_cvt(Wih + (size_t)row * DIM + xc * 32 + q * 8);
    }
  }

  float bias[4][4], c_st[4], hsum[4];
  #pragma unroll
  for (int mt = 0; mt < 4; ++mt)
    #pragma unroll
    for (int r = 0; r < 4; ++r) {
      const int row = mt * HID + J + q * 4 + r;
      bias[mt][r] = bih[row] + bhh[row];
    }
  #pragma unroll
  for (int r = 0; r < 4; ++r) { c_st[r] = 0.f; hsum[r] = 0.f; }

  unsigned int* mycnt = cnt + g * 32;           // 128B-padded counters
  const float*  Xb    = X + (size_t)b_my * T_STEPS * DIM;

  for (int t = 0; t < T_STEPS; ++t) {
    f32x4 acc[4];
    #pragma unroll
    for (int mt = 0; mt < 4; ++mt) acc[mt] = (f32x4){0.f, 0.f, 0.f, 0.f};

    // x-projection part first: independent of h, overlaps barrier propagation
    #pragma unroll
    for (int lx = 0; lx < 2; ++lx) {
      const int xc = khalf * 2 + lx;
      half8 xb = load8_cvt(Xb + t * DIM + xc * 32 + q * 8);
      #pragma unroll
      for (int mt = 0; mt < 4; ++mt)
        acc[mt] = __builtin_amdgcn_mfma_f32_16x16x32_f16(wih[lx][mt], xb, acc[mt], 0, 0, 0);
    }

    // wait for h(t) from the whole group
    if (t > 0) {
      const unsigned int target = (unsigned int)(GBLK * t);
      while (__hip_atomic_load(mycnt, __ATOMIC_RELAXED, __HIP_MEMORY_SCOPE_AGENT) < target) { }
      __threadfence();  // acquire: invalidate L1/L2 so h loads see remote writes
    }

    // recurrent part: B-frags straight from global h buffer (fp16)
    const _Float16* hb = hbuf + (size_t)(t & 1) * (BATCH * HID)
                              + (size_t)b_my * HID + khalf * 256 + q * 8;
    half8 bfrag[8];
    #pragma unroll
    for (int lc = 0; lc < 8; ++lc) bfrag[lc] = *(const half8*)(hb + lc * 32);
    #pragma unroll
    for (int lc = 0; lc < 8; ++lc) {
      #pragma unroll
      for (int mt = 0; mt < 4; ++mt)
        acc[mt] = __builtin_amdgcn_mfma_f32_16x16x32_f16(whh[lc][mt], bfrag[lc], acc[mt], 0, 0, 0);
    }

    // combine K-halves: wave1 -> LDS -> wave0
    if (khalf == 1) {
      #pragma unroll
      for (int mt = 0; mt < 4; ++mt)
        #pragma unroll
        for (int r = 0; r < 4; ++r)
          scratch[(mt * 4 + r) * 64 + lane] = acc[mt][r];
    }
    __syncthreads();
    if (khalf == 0) {
      #pragma unroll
      for (int mt = 0; mt < 4; ++mt)
        #pragma unroll
        for (int r = 0; r < 4; ++r)
          acc[mt][r] += scratch[(mt * 4 + r) * 64 + lane] + bias[mt][r];
      half4 hv;
      #pragma unroll
      for (int r = 0; r < 4; ++r) {
        const float ig = 1.f / (1.f + __expf(-acc[0][r]));
        const float fg = 1.f / (1.f + __expf(-acc[1][r]));
        const float gg = tanhf(acc[2][r]);
        const float og = 1.f / (1.f + __expf(-acc[3][r]));
        const float cc = fg * c_st[r] + ig * gg;
        c_st[r] = cc;
        const float h = og * tanhf(cc);
        hsum[r] += h;
        hv[r] = (_Float16)h;
      }
      // write h(t+1): 4 consecutive units, 8B store
      *(half4*)(hbuf + (size_t)((t + 1) & 1) * (BATCH * HID)
                     + (size_t)b_my * HID + J + q * 4) = hv;
    }
    __syncthreads();  // h stores drained (vmcnt0) + scratch consumed
    if (t + 1 < T_STEPS && tid == 64) {
      __threadfence();  // release: flush this XCD's L2 before signaling
      __hip_atomic_fetch_add(mycnt, 1u, __ATOMIC_RELAXED, __HIP_MEMORY_SCOPE_AGENT);
    }
  }

  // epilogue: logits += mean_h * W_lin^T (bias pre-set by init kernel)
  if (khalf == 0) {
    const float inv = 1.0f / (float)T_STEPS;
    float m[4];
    #pragma unroll
    for (int r = 0; r < 4; ++r) m[r] = hsum[r] * inv;
    #pragma unroll
    for (int cls = 0; cls < 10; ++cls) {
      f32x4 wl = *(const f32x4*)(Wlin + (size_t)cls * HID + J + q * 4);
      float p = m[0] * wl[0] + m[1] * wl[1] + m[2] * wl[2] + m[3] * wl[3];
      p += __shfl_xor(p, 16, 64);
      p += __shfl_xor(p, 32, 64);
      if (q == 0) atomicAdd(out + b_my * 10 + cls, p);
    }
  }
}

__global__ void init_out(const float* __restrict__ blin, float* __restrict__ out) {
  const int i = blockIdx.x * blockDim.x + threadIdx.x;
  if (i < BATCH * 10) out[i] = blin[i % 10];
}

extern "C" void kernel_launch(void* const* d_in, const int* in_sizes, int n_in,
                              void* d_out, int out_size, void* d_ws, size_t ws_size,
                              hipStream_t stream) {
  const float* X    = (const float*)d_in[0];
  const float* Wih  = (const float*)d_in[1];
  const float* Whh  = (const float*)d_in[2];
  const float* bih  = (const float*)d_in[3];
  const float* bhh  = (const float*)d_in[4];
  const float* Wlin = (const float*)d_in[5];
  const float* blin = (const float*)d_in[6];
  float* out = (float*)d_out;

  if (ws_size < (size_t)WS_NEEDED) return;  // refuse to corrupt memory

  _Float16*     hbuf = (_Float16*)d_ws;
  unsigned int* cnt  = (unsigned int*)((char*)d_ws + CNT_OFF);

  hipMemsetAsync(d_ws, 0, WS_NEEDED, stream);
  init_out<<<10, 256, 0, stream>>>(blin, out);
  lstm_persistent<<<512, 128, 0, stream>>>(X, Wih, Whh, bih, bhh, Wlin, out, hbuf, cnt);
}

// Round 2
// 5584.925 us; speedup vs baseline: 2.7803x; 2.7803x over previous
//
#include <hip/hip_runtime.h>
#include <stdint.h>

// LSTM: B=256, T=512, D=128, H=512, C=10
// Persistent kernel: 512 blocks x 1 wave (64 thr). 16 groups x 32 blocks.
// Group owns 16 batches; block owns 16 hidden units (64 gate rows), full K=640.
// W_ih/W_hh slices in VGPRs (fp16 MFMA A-frags, ~320 VGPR). h exchanged via
// relaxed agent-scope atomics (coherent at L3, no L2 writeback/invalidate).

#define T_STEPS 512
#define BATCH   256
#define DIM     128
#define HID     512
#define NGRP    16
#define GBLK    32
#define BT      16

typedef _Float16 half8 __attribute__((ext_vector_type(8)));
typedef _Float16 half4 __attribute__((ext_vector_type(4)));
typedef float    f32x4 __attribute__((ext_vector_type(4)));

#define HBUF_HALFS   (2 * BATCH * HID)
#define CNT_OFF      (HBUF_HALFS * 2)          // 524288 bytes
#define WS_NEEDED    (CNT_OFF + NGRP * 128)

__device__ __forceinline__ half8 load8_cvt(const float* p) {
  const f32x4* q = (const f32x4*)p;
  f32x4 a = q[0], b = q[1];
  half8 r;
  r[0]=(_Float16)a[0]; r[1]=(_Float16)a[1]; r[2]=(_Float16)a[2]; r[3]=(_Float16)a[3];
  r[4]=(_Float16)b[0]; r[5]=(_Float16)b[1]; r[6]=(_Float16)b[2]; r[7]=(_Float16)b[3];
  return r;
}

union h4u { unsigned long long u; half4 h; };

__global__ __launch_bounds__(64, 1) void lstm_persistent(
    const float* __restrict__ X,   const float* __restrict__ Wih,
    const float* __restrict__ Whh, const float* __restrict__ bih,
    const float* __restrict__ bhh, const float* __restrict__ Wlin,
    float* __restrict__ out, _Float16* __restrict__ hbuf,
    unsigned int* __restrict__ cnt)
{
  const int lane  = threadIdx.x;     // 64 threads = 1 wave
  const int col   = lane & 15;       // batch-within-group (B/C col), also W A-frag row
  const int q     = lane >> 4;       // 0..3 (k-subchunk / C-row quad)
  const int bid   = blockIdx.x;
  const int g     = bid & 15;        // group (blocks of a group share bid%8 XCD heuristic)
  const int J     = (bid >> 4) * 16; // hidden-unit base owned by this block
  const int b_my  = g * BT + col;    // this lane's batch

  // ---- W fragments into registers (once) ----
  half8 whh[16][4];                  // [k-chunk of 32][gate] : 256 VGPR
  half8 wih[4][4];                   // 64 VGPR
  #pragma unroll
  for (int kc = 0; kc < 16; ++kc)
    #pragma unroll
    for (int mt = 0; mt < 4; ++mt) {
      const int row = mt * HID + J + col;
      whh[kc][mt] = load8_cvt(Whh + (size_t)row * HID + kc * 32 + q * 8);
    }
  #pragma unroll
  for (int xc = 0; xc < 4; ++xc)
    #pragma unroll
    for (int mt = 0; mt < 4; ++mt) {
      const int row = mt * HID + J + col;
      wih[xc][mt] = load8_cvt(Wih + (size_t)row * DIM + xc * 32 + q * 8);
    }

  float bias[4][4], c_st[4], hsum[4];
  #pragma unroll
  for (int mt = 0; mt < 4; ++mt)
    #pragma unroll
    for (int r = 0; r < 4; ++r) {
      const int row = mt * HID + J + q * 4 + r;
      bias[mt][r] = bih[row] + bhh[row];
    }
  #pragma unroll
  for (int r = 0; r < 4; ++r) { c_st[r] = 0.f; hsum[r] = 0.f; }

  unsigned int* mycnt = cnt + g * 32;
  const float*  Xb    = X + (size_t)b_my * T_STEPS * DIM;

  for (int t = 0; t < T_STEPS; ++t) {
    f32x4 acc[4];
    #pragma unroll
    for (int mt = 0; mt < 4; ++mt) acc[mt] = (f32x4){0.f, 0.f, 0.f, 0.f};

    // x-projection first: independent of h, overlaps barrier propagation
    #pragma unroll
    for (int xc = 0; xc < 4; ++xc) {
      half8 xb = load8_cvt(Xb + t * DIM + xc * 32 + q * 8);
      #pragma unroll
      for (int mt = 0; mt < 4; ++mt)
        acc[mt] = __builtin_amdgcn_mfma_f32_16x16x32_f16(wih[xc][mt], xb, acc[mt], 0, 0, 0);
    }

    // wait for h(t) from the whole group (relaxed spin; no cache maintenance)
    if (t > 0) {
      const unsigned int target = (unsigned int)(GBLK * t);
      while (__hip_atomic_load(mycnt, __ATOMIC_RELAXED, __HIP_MEMORY_SCOPE_AGENT) < target)
        __builtin_amdgcn_s_sleep(1);
      __builtin_amdgcn_sched_barrier(0);  // nothing crosses the spin
    }

    // recurrent part: h B-frags via relaxed agent atomic loads (L3-coherent)
    const _Float16* hb = hbuf + (size_t)(t & 1) * (BATCH * HID) + (size_t)b_my * HID;
    half8 bfrag[16];
    #pragma unroll
    for (int kc = 0; kc < 16; ++kc) {
      h4u lo, hi;
      const unsigned long long* p =
          (const unsigned long long*)(hb + kc * 32 + q * 8);
      lo.u = __hip_atomic_load(p,     __ATOMIC_RELAXED, __HIP_MEMORY_SCOPE_AGENT);
      hi.u = __hip_atomic_load(p + 1, __ATOMIC_RELAXED, __HIP_MEMORY_SCOPE_AGENT);
      half8 f;
      f[0]=lo.h[0]; f[1]=lo.h[1]; f[2]=lo.h[2]; f[3]=lo.h[3];
      f[4]=hi.h[0]; f[5]=hi.h[1]; f[6]=hi.h[2]; f[7]=hi.h[3];
      bfrag[kc] = f;
    }
    #pragma unroll
    for (int kc = 0; kc < 16; ++kc)
      #pragma unroll
      for (int mt = 0; mt < 4; ++mt)
        acc[mt] = __builtin_amdgcn_mfma_f32_16x16x32_f16(whh[kc][mt], bfrag[kc], acc[mt], 0, 0, 0);

    // gates -> c,h ; each lane owns units J+q*4..+3 for batch col
    h4u hv;
    #pragma unroll
    for (int r = 0; r < 4; ++r) {
      const float ig = 1.f / (1.f + __expf(-(acc[0][r] + bias[0][r])));
      const float fg = 1.f / (1.f + __expf(-(acc[1][r] + bias[1][r])));
      const float gg = tanhf(acc[2][r] + bias[2][r]);
      const float og = 1.f / (1.f + __expf(-(acc[3][r] + bias[3][r])));
      const float cc = fg * c_st[r] + ig * gg;
      c_st[r] = cc;
      const float h = og * tanhf(cc);
      hsum[r] += h;
      hv.h[r] = (_Float16)h;
    }
    // h(t+1) store: relaxed agent atomic (bypasses L2, lands in L3)
    unsigned long long* hw =
        (unsigned long long*)(hbuf + (size_t)((t + 1) & 1) * (BATCH * HID)
                              + (size_t)b_my * HID + J + q * 4);
    __hip_atomic_store(hw, hv.u, __ATOMIC_RELAXED, __HIP_MEMORY_SCOPE_AGENT);

    if (t + 1 < T_STEPS && lane == 0) {
      // RELEASE: s_waitcnt vmcnt(0) orders the h atomic stores before the signal
      __hip_atomic_fetch_add(mycnt, 1u, __ATOMIC_RELEASE, __HIP_MEMORY_SCOPE_AGENT);
    }
  }

  // epilogue: logits += mean_h * W_lin^T (bias pre-set by init kernel)
  const float inv = 1.0f / (float)T_STEPS;
  float m[4];
  #pragma unroll
  for (int r = 0; r < 4; ++r) m[r] = hsum[r] * inv;
  #pragma unroll
  for (int cls = 0; cls < 10; ++cls) {
    f32x4 wl = *(const f32x4*)(Wlin + (size_t)cls * HID + J + q * 4);
    float p = m[0] * wl[0] + m[1] * wl[1] + m[2] * wl[2] + m[3] * wl[3];
    p += __shfl_xor(p, 16, 64);
    p += __shfl_xor(p, 32, 64);
    if (q == 0) atomicAdd(out + b_my * 10 + cls, p);
  }
}

__global__ void init_out(const float* __restrict__ blin, float* __restrict__ out) {
  const int i = blockIdx.x * blockDim.x + threadIdx.x;
  if (i < BATCH * 10) out[i] = blin[i % 10];
}

extern "C" void kernel_launch(void* const* d_in, const int* in_sizes, int n_in,
                              void* d_out, int out_size, void* d_ws, size_t ws_size,
                              hipStream_t stream) {
  const float* X    = (const float*)d_in[0];
  const float* Wih  = (const float*)d_in[1];
  const float* Whh  = (const float*)d_in[2];
  const float* bih  = (const float*)d_in[3];
  const float* bhh  = (const float*)d_in[4];
  const float* Wlin = (const float*)d_in[5];
  const float* blin = (const float*)d_in[6];
  float* out = (float*)d_out;

  if (ws_size < (size_t)WS_NEEDED) return;

  _Float16*     hbuf = (_Float16*)d_ws;
  unsigned int* cnt  = (unsigned int*)((char*)d_ws + CNT_OFF);

  hipMemsetAsync(d_ws, 0, WS_NEEDED, stream);
  init_out<<<10, 256, 0, stream>>>(blin, out);
  lstm_persistent<<<512, 64, 0, stream>>>(X, Wih, Whh, bih, bhh, Wlin, out, hbuf, cnt);
}

// Round 3
// 4569.732 us; speedup vs baseline: 3.3980x; 1.2222x over previous
//
#include <hip/hip_runtime.h>
#include <stdint.h>

// LSTM: B=256, T=512, D=128, H=512, C=10
// Persistent kernel: 128 blocks x 4 waves (256 thr). 16 groups x 8 blocks.
// Group owns 16 batches; each wave owns 16 hidden units (full K=640), so a
// block owns 64 units. W_ih/W_hh in unified VGPR/AGPR file (~320 regs/wave).
// h exchanged via relaxed agent-scope atomics (L3-coherent). Per-block FLAG
// stores (no RMW) + coalesced 8-flag poll replace the shared counter.

#define T_STEPS 512
#define BATCH   256
#define DIM     128
#define HID     512
#define NGRP    16
#define BPG     8     // blocks per group
#define BT      16    // batches per group

typedef _Float16 half8 __attribute__((ext_vector_type(8)));
typedef _Float16 half4 __attribute__((ext_vector_type(4)));
typedef float    f32x4 __attribute__((ext_vector_type(4)));

#define HBUF_HALFS   (2 * BATCH * HID)
#define CNT_OFF      (HBUF_HALFS * 2)          // 524288 bytes
#define WS_NEEDED    (CNT_OFF + NGRP * 128)

__device__ __forceinline__ half8 load8_cvt(const float* p) {
  const f32x4* q = (const f32x4*)p;
  f32x4 a = q[0], b = q[1];
  half8 r;
  r[0]=(_Float16)a[0]; r[1]=(_Float16)a[1]; r[2]=(_Float16)a[2]; r[3]=(_Float16)a[3];
  r[4]=(_Float16)b[0]; r[5]=(_Float16)b[1]; r[6]=(_Float16)b[2]; r[7]=(_Float16)b[3];
  return r;
}

union h4u { unsigned long long u; half4 h; };

__global__ __launch_bounds__(256, 1) void lstm_persistent(
    const float* __restrict__ X,   const float* __restrict__ Wih,
    const float* __restrict__ Whh, const float* __restrict__ bih,
    const float* __restrict__ bhh, const float* __restrict__ Wlin,
    float* __restrict__ out, _Float16* __restrict__ hbuf,
    unsigned int* __restrict__ flg)
{
  const int tid   = threadIdx.x;
  const int w     = tid >> 6;        // wave 0..3
  const int lane  = tid & 63;
  const int col   = lane & 15;       // batch-within-group (B/C col), W A-frag row
  const int q     = lane >> 4;       // 0..3
  const int bid   = blockIdx.x;
  const int g     = bid & 15;        // group; all 8 blocks of a group share bid%8 (XCD heuristic)
  const int blk   = bid >> 4;        // 0..7 within group
  const int J     = blk * 64 + w * 16;  // hidden-unit base owned by this wave
  const int b_my  = g * BT + col;    // this lane's batch

  // ---- W fragments into registers (once) ----
  half8 whh[16][4];                  // [k-chunk of 32][gate]
  half8 wih[4][4];
  #pragma unroll
  for (int kc = 0; kc < 16; ++kc)
    #pragma unroll
    for (int mt = 0; mt < 4; ++mt) {
      const int row = mt * HID + J + col;
      whh[kc][mt] = load8_cvt(Whh + (size_t)row * HID + kc * 32 + q * 8);
    }
  #pragma unroll
  for (int xc = 0; xc < 4; ++xc)
    #pragma unroll
    for (int mt = 0; mt < 4; ++mt) {
      const int row = mt * HID + J + col;
      wih[xc][mt] = load8_cvt(Wih + (size_t)row * DIM + xc * 32 + q * 8);
    }

  float bias[4][4], c_st[4], hsum[4];
  #pragma unroll
  for (int mt = 0; mt < 4; ++mt)
    #pragma unroll
    for (int r = 0; r < 4; ++r) {
      const int row = mt * HID + J + q * 4 + r;
      bias[mt][r] = bih[row] + bhh[row];
    }
  #pragma unroll
  for (int r = 0; r < 4; ++r) { c_st[r] = 0.f; hsum[r] = 0.f; }

  unsigned int* myflg = flg + g * 32;   // 8 flags used, 128B stride per group
  const float*  Xb    = X + (size_t)b_my * T_STEPS * DIM;

  for (int t = 0; t < T_STEPS; ++t) {
    f32x4 acc[4];
    #pragma unroll
    for (int mt = 0; mt < 4; ++mt) acc[mt] = (f32x4){0.f, 0.f, 0.f, 0.f};

    // x-projection first: independent of h, overlaps flag propagation
    #pragma unroll
    for (int xc = 0; xc < 4; ++xc) {
      half8 xb = load8_cvt(Xb + t * DIM + xc * 32 + q * 8);
      #pragma unroll
      for (int mt = 0; mt < 4; ++mt)
        acc[mt] = __builtin_amdgcn_mfma_f32_16x16x32_f16(wih[xc][mt], xb, acc[mt], 0, 0, 0);
    }

    // wait for h(t): all 8 producer blocks of this group must have flag >= t.
    // One coalesced 4B load per lane (lane&7 selects flag) + ballot.
    if (t > 0) {
      const unsigned int target = (unsigned int)t;
      for (;;) {
        unsigned int v = __hip_atomic_load(myflg + (lane & 7), __ATOMIC_RELAXED,
                                           __HIP_MEMORY_SCOPE_AGENT);
        if (__all(v >= target)) break;
        __builtin_amdgcn_s_sleep(1);
      }
      __builtin_amdgcn_sched_barrier(0);  // nothing crosses the spin
    }

    // recurrent part: h B-frags via relaxed agent atomic loads (L3-coherent)
    const _Float16* hb = hbuf + (size_t)(t & 1) * (BATCH * HID) + (size_t)b_my * HID;
    half8 bfrag[16];
    #pragma unroll
    for (int kc = 0; kc < 16; ++kc) {
      h4u lo, hi;
      const unsigned long long* p =
          (const unsigned long long*)(hb + kc * 32 + q * 8);
      lo.u = __hip_atomic_load(p,     __ATOMIC_RELAXED, __HIP_MEMORY_SCOPE_AGENT);
      hi.u = __hip_atomic_load(p + 1, __ATOMIC_RELAXED, __HIP_MEMORY_SCOPE_AGENT);
      half8 f;
      f[0]=lo.h[0]; f[1]=lo.h[1]; f[2]=lo.h[2]; f[3]=lo.h[3];
      f[4]=hi.h[0]; f[5]=hi.h[1]; f[6]=hi.h[2]; f[7]=hi.h[3];
      bfrag[kc] = f;
    }
    #pragma unroll
    for (int kc = 0; kc < 16; ++kc)
      #pragma unroll
      for (int mt = 0; mt < 4; ++mt)
        acc[mt] = __builtin_amdgcn_mfma_f32_16x16x32_f16(whh[kc][mt], bfrag[kc], acc[mt], 0, 0, 0);

    // gates -> c,h ; each lane owns units J+q*4..+3 for batch col
    h4u hv;
    #pragma unroll
    for (int r = 0; r < 4; ++r) {
      const float ig = 1.f / (1.f + __expf(-(acc[0][r] + bias[0][r])));
      const float fg = 1.f / (1.f + __expf(-(acc[1][r] + bias[1][r])));
      const float gg = tanhf(acc[2][r] + bias[2][r]);
      const float og = 1.f / (1.f + __expf(-(acc[3][r] + bias[3][r])));
      const float cc = fg * c_st[r] + ig * gg;
      c_st[r] = cc;
      const float h = og * tanhf(cc);
      hsum[r] += h;
      hv.h[r] = (_Float16)h;
    }
    // h(t+1) store: relaxed agent atomic (bypasses L2, lands in L3)
    unsigned long long* hw =
        (unsigned long long*)(hbuf + (size_t)((t + 1) & 1) * (BATCH * HID)
                              + (size_t)b_my * HID + J + q * 4);
    __hip_atomic_store(hw, hv.u, __ATOMIC_RELAXED, __HIP_MEMORY_SCOPE_AGENT);

    // all 4 waves' h stores drained (syncthreads waits vmcnt(0)), then ONE
    // release flag store per block — no RMW, no serialization.
    __syncthreads();
    if (t + 1 < T_STEPS && tid == 0)
      __hip_atomic_store(myflg + blk, (unsigned int)(t + 1), __ATOMIC_RELEASE,
                         __HIP_MEMORY_SCOPE_AGENT);
  }

  // epilogue: logits += mean_h * W_lin^T (bias pre-set by init kernel)
  const float inv = 1.0f / (float)T_STEPS;
  float m[4];
  #pragma unroll
  for (int r = 0; r < 4; ++r) m[r] = hsum[r] * inv;
  #pragma unroll
  for (int cls = 0; cls < 10; ++cls) {
    f32x4 wl = *(const f32x4*)(Wlin + (size_t)cls * HID + J + q * 4);
    float p = m[0] * wl[0] + m[1] * wl[1] + m[2] * wl[2] + m[3] * wl[3];
    p += __shfl_xor(p, 16, 64);
    p += __shfl_xor(p, 32, 64);
    if (q == 0) atomicAdd(out + b_my * 10 + cls, p);
  }
}

__global__ void init_out(const float* __restrict__ blin, float* __restrict__ out) {
  const int i = blockIdx.x * blockDim.x + threadIdx.x;
  if (i < BATCH * 10) out[i] = blin[i % 10];
}

extern "C" void kernel_launch(void* const* d_in, const int* in_sizes, int n_in,
                              void* d_out, int out_size, void* d_ws, size_t ws_size,
                              hipStream_t stream) {
  const float* X    = (const float*)d_in[0];
  const float* Wih  = (const float*)d_in[1];
  const float* Whh  = (const float*)d_in[2];
  const float* bih  = (const float*)d_in[3];
  const float* bhh  = (const float*)d_in[4];
  const float* Wlin = (const float*)d_in[5];
  const float* blin = (const float*)d_in[6];
  float* out = (float*)d_out;

  if (ws_size < (size_t)WS_NEEDED) return;

  _Float16*     hbuf = (_Float16*)d_ws;
  unsigned int* flg  = (unsigned int*)((char*)d_ws + CNT_OFF);

  hipMemsetAsync(d_ws, 0, WS_NEEDED, stream);
  init_out<<<10, 256, 0, stream>>>(blin, out);
  lstm_persistent<<<128, 256, 0, stream>>>(X, Wih, Whh, bih, bhh, Wlin, out, hbuf, flg);
}

// Round 4
// 3691.476 us; speedup vs baseline: 4.2064x; 1.2379x over previous
//
#include <hip/hip_runtime.h>
#include <stdint.h>

// LSTM: B=256, T=512, D=128, H=512, C=10
// Persistent kernel: 128 blocks x 4 waves (256 thr). 16 groups x 8 blocks.
// Group owns 16 batches; each wave owns 16 hidden units (full K=640).
// W_ih/W_hh in unified VGPR/AGPR file (~320 regs/wave). h exchanged via
// relaxed agent-scope atomics (L3-coherent, sc1 bypasses L1/L2).
// Sync: PER-WAVE flags (32 dwords = one 128B line per group). Producer wave:
// h stores -> s_waitcnt vmcnt(0) (store-ack at coherence point) -> relaxed
// flag store. No RELEASE (avoids buffer_wbl2), no __syncthreads in the loop.

#define T_STEPS 512
#define BATCH   256
#define DIM     128
#define HID     512
#define NGRP    16
#define BT      16    // batches per group

typedef _Float16 half8 __attribute__((ext_vector_type(8)));
typedef _Float16 half4 __attribute__((ext_vector_type(4)));
typedef float    f32x4 __attribute__((ext_vector_type(4)));

#define HBUF_HALFS   (2 * BATCH * HID)
#define CNT_OFF      (HBUF_HALFS * 2)          // 524288 bytes
#define WS_NEEDED    (CNT_OFF + NGRP * 128)

__device__ __forceinline__ half8 load8_cvt(const float* p) {
  const f32x4* q = (const f32x4*)p;
  f32x4 a = q[0], b = q[1];
  half8 r;
  r[0]=(_Float16)a[0]; r[1]=(_Float16)a[1]; r[2]=(_Float16)a[2]; r[3]=(_Float16)a[3];
  r[4]=(_Float16)b[0]; r[5]=(_Float16)b[1]; r[6]=(_Float16)b[2]; r[7]=(_Float16)b[3];
  return r;
}

__device__ __forceinline__ float fsig(float x) {
  return __builtin_amdgcn_rcpf(1.f + __expf(-x));
}
__device__ __forceinline__ float ftanh(float x) {
  // tanh(x) = 1 - 2/(1+e^{2x}); exact at +/-inf, ~1e-7 rel err from rcp
  return 1.f - 2.f * __builtin_amdgcn_rcpf(1.f + __expf(2.f * x));
}

union h4u { unsigned long long u; half4 h; };

__global__ __launch_bounds__(256, 1) void lstm_persistent(
    const float* __restrict__ X,   const float* __restrict__ Wih,
    const float* __restrict__ Whh, const float* __restrict__ bih,
    const float* __restrict__ bhh, const float* __restrict__ Wlin,
    float* __restrict__ out, _Float16* __restrict__ hbuf,
    unsigned int* __restrict__ flg)
{
  const int tid   = threadIdx.x;
  const int w     = tid >> 6;        // wave 0..3 (independent; no intra-block sync)
  const int lane  = tid & 63;
  const int col   = lane & 15;       // batch-within-group (B/C col), W A-frag row
  const int q     = lane >> 4;       // 0..3
  const int bid   = blockIdx.x;
  const int g     = bid & 15;        // group
  const int blk   = bid >> 4;        // 0..7 within group
  const int J     = blk * 64 + w * 16;  // hidden-unit base owned by this wave
  const int wid   = blk * 4 + w;     // wave id in group, 0..31
  const int b_my  = g * BT + col;    // this lane's batch

  // ---- W fragments into registers (once) ----
  half8 whh[16][4];                  // [k-chunk of 32][gate]
  half8 wih[4][4];
  #pragma unroll
  for (int kc = 0; kc < 16; ++kc)
    #pragma unroll
    for (int mt = 0; mt < 4; ++mt) {
      const int row = mt * HID + J + col;
      whh[kc][mt] = load8_cvt(Whh + (size_t)row * HID + kc * 32 + q * 8);
    }
  #pragma unroll
  for (int xc = 0; xc < 4; ++xc)
    #pragma unroll
    for (int mt = 0; mt < 4; ++mt) {
      const int row = mt * HID + J + col;
      wih[xc][mt] = load8_cvt(Wih + (size_t)row * DIM + xc * 32 + q * 8);
    }

  float bias[4][4], c_st[4], hsum[4];
  #pragma unroll
  for (int mt = 0; mt < 4; ++mt)
    #pragma unroll
    for (int r = 0; r < 4; ++r) {
      const int row = mt * HID + J + q * 4 + r;
      bias[mt][r] = bih[row] + bhh[row];
    }
  #pragma unroll
  for (int r = 0; r < 4; ++r) { c_st[r] = 0.f; hsum[r] = 0.f; }

  unsigned int* myflg = flg + g * 32;   // 32 per-wave flags = one 128B line
  const float*  Xb    = X + (size_t)b_my * T_STEPS * DIM;

  for (int t = 0; t < T_STEPS; ++t) {
    f32x4 acc[4];
    #pragma unroll
    for (int mt = 0; mt < 4; ++mt) acc[mt] = (f32x4){0.f, 0.f, 0.f, 0.f};

    // x-projection first: independent of h, overlaps flag propagation
    #pragma unroll
    for (int xc = 0; xc < 4; ++xc) {
      half8 xb = load8_cvt(Xb + t * DIM + xc * 32 + q * 8);
      #pragma unroll
      for (int mt = 0; mt < 4; ++mt)
        acc[mt] = __builtin_amdgcn_mfma_f32_16x16x32_f16(wih[xc][mt], xb, acc[mt], 0, 0, 0);
    }

    // wait for h(t): all 32 producer waves of this group at flag >= t.
    // Tight spin (no co-resident waves to yield to at this occupancy).
    if (t > 0) {
      const unsigned int target = (unsigned int)t;
      for (;;) {
        unsigned int v = __hip_atomic_load(myflg + (lane & 31), __ATOMIC_RELAXED,
                                           __HIP_MEMORY_SCOPE_AGENT);
        if (__all(v >= target)) break;
      }
      __builtin_amdgcn_sched_barrier(0);  // nothing crosses the spin
    }

    // recurrent part: h B-frags via relaxed agent atomic loads (L3-coherent)
    const _Float16* hb = hbuf + (size_t)(t & 1) * (BATCH * HID) + (size_t)b_my * HID;
    half8 bfrag[16];
    #pragma unroll
    for (int kc = 0; kc < 16; ++kc) {
      h4u lo, hi;
      const unsigned long long* p =
          (const unsigned long long*)(hb + kc * 32 + q * 8);
      lo.u = __hip_atomic_load(p,     __ATOMIC_RELAXED, __HIP_MEMORY_SCOPE_AGENT);
      hi.u = __hip_atomic_load(p + 1, __ATOMIC_RELAXED, __HIP_MEMORY_SCOPE_AGENT);
      half8 f;
      f[0]=lo.h[0]; f[1]=lo.h[1]; f[2]=lo.h[2]; f[3]=lo.h[3];
      f[4]=hi.h[0]; f[5]=hi.h[1]; f[6]=hi.h[2]; f[7]=hi.h[3];
      bfrag[kc] = f;
    }
    #pragma unroll
    for (int kc = 0; kc < 16; ++kc)
      #pragma unroll
      for (int mt = 0; mt < 4; ++mt)
        acc[mt] = __builtin_amdgcn_mfma_f32_16x16x32_f16(whh[kc][mt], bfrag[kc], acc[mt], 0, 0, 0);

    // gates -> c,h ; each lane owns units J+q*4..+3 for batch col
    h4u hv;
    #pragma unroll
    for (int r = 0; r < 4; ++r) {
      const float ig = fsig(acc[0][r] + bias[0][r]);
      const float fg = fsig(acc[1][r] + bias[1][r]);
      const float gg = ftanh(acc[2][r] + bias[2][r]);
      const float og = fsig(acc[3][r] + bias[3][r]);
      const float cc = fg * c_st[r] + ig * gg;
      c_st[r] = cc;
      const float h = og * ftanh(cc);
      hsum[r] += h;
      hv.h[r] = (_Float16)h;
    }
    // h(t+1) store: relaxed agent atomic (bypasses L2, coherent at L3)
    unsigned long long* hw =
        (unsigned long long*)(hbuf + (size_t)((t + 1) & 1) * (BATCH * HID)
                              + (size_t)b_my * HID + J + q * 4);
    __hip_atomic_store(hw, hv.u, __ATOMIC_RELAXED, __HIP_MEMORY_SCOPE_AGENT);

    // Manual release: wave-wide store-ack drain, then relaxed per-wave flag.
    // (All cross-CU data is sc1 atomics -> no dirty L2 -> no wbl2 needed.)
    if (t + 1 < T_STEPS) {
      asm volatile("s_waitcnt vmcnt(0)" ::: "memory");
      if (lane == 0)
        __hip_atomic_store(myflg + wid, (unsigned int)(t + 1), __ATOMIC_RELAXED,
                           __HIP_MEMORY_SCOPE_AGENT);
    }
  }

  // epilogue: logits += mean_h * W_lin^T (bias pre-set by init kernel)
  const float inv = 1.0f / (float)T_STEPS;
  float m[4];
  #pragma unroll
  for (int r = 0; r < 4; ++r) m[r] = hsum[r] * inv;
  #pragma unroll
  for (int cls = 0; cls < 10; ++cls) {
    f32x4 wl = *(const f32x4*)(Wlin + (size_t)cls * HID + J + q * 4);
    float p = m[0] * wl[0] + m[1] * wl[1] + m[2] * wl[2] + m[3] * wl[3];
    p += __shfl_xor(p, 16, 64);
    p += __shfl_xor(p, 32, 64);
    if (q == 0) atomicAdd(out + b_my * 10 + cls, p);
  }
}

__global__ void init_out(const float* __restrict__ blin, float* __restrict__ out) {
  const int i = blockIdx.x * blockDim.x + threadIdx.x;
  if (i < BATCH * 10) out[i] = blin[i % 10];
}

extern "C" void kernel_launch(void* const* d_in, const int* in_sizes, int n_in,
                              void* d_out, int out_size, void* d_ws, size_t ws_size,
                              hipStream_t stream) {
  const float* X    = (const float*)d_in[0];
  const float* Wih  = (const float*)d_in[1];
  const float* Whh  = (const float*)d_in[2];
  const float* bih  = (const float*)d_in[3];
  const float* bhh  = (const float*)d_in[4];
  const float* Wlin = (const float*)d_in[5];
  const float* blin = (const float*)d_in[6];
  float* out = (float*)d_out;

  if (ws_size < (size_t)WS_NEEDED) return;

  _Float16*     hbuf = (_Float16*)d_ws;
  unsigned int* flg  = (unsigned int*)((char*)d_ws + CNT_OFF);

  hipMemsetAsync(d_ws, 0, WS_NEEDED, stream);
  init_out<<<10, 256, 0, stream>>>(blin, out);
  lstm_persistent<<<128, 256, 0, stream>>>(X, Wih, Whh, bih, bhh, Wlin, out, hbuf, flg);
}